// Round 6
// baseline (392.847 us; speedup 1.0000x reference)
//
#include <hip/hip_runtime.h>
#include <hip/hip_bf16.h>

// SAGE 2-layer: N nodes, E edges, D=256. FP32 inputs, bf16 MFMA pipeline.
// A-buffer abuf[N,512] = [mean | x] (layer1) then [mean2 | h] (layer2, in place).
// Combined weights Wc[256 out, 512 k].
//
// R5: agg 55.4us, latency-bound (VALU 26%, hbm 46%, issue-time ~4us) with
// intra-wave divergence (2 nodes/wave, independent degree loops). Now:
// one wave per node — halves process neighbors i/i+1 of the SAME node,
// uniform trip count, unroll x4 (8 neighbors in flight), __shfl_xor(32)
// combine. 2x wave count -> 2x aggregate MLP at unchanged traffic.

#define DD 256

typedef unsigned short ushort_t;
using bf16x8 = __attribute__((ext_vector_type(8))) short;
using f32x4  = __attribute__((ext_vector_type(4))) float;

static __device__ __forceinline__ float b2f(ushort_t u) {
    __hip_bfloat16 h = *reinterpret_cast<__hip_bfloat16*>(&u);
    return __bfloat162float(h);
}
static __device__ __forceinline__ ushort_t f2b(float f) {
    __hip_bfloat16 h = __float2bfloat16(f);
    return *reinterpret_cast<ushort_t*>(&h);
}

static __device__ __forceinline__ void load16(const ushort_t* g, ushort_t* l) {
    __builtin_amdgcn_global_load_lds(
        (const __attribute__((address_space(1))) unsigned*)(g),
        (__attribute__((address_space(3))) unsigned*)(l),
        16, 0, 0);
}

// ---------------- casts (fp32 -> bf16, into combined layouts) ----------------

// x[N,256] -> abuf[:, 256:512]
__global__ void cast_x_kernel(const float* __restrict__ in, ushort_t* __restrict__ abuf,
                              int n) {
    int i = (blockIdx.x * 256 + threadIdx.x) * 8;
    if (i + 8 > n) return;
    int row = i >> 8, col = i & 255;
    float4 a = *(const float4*)(in + i);
    float4 b = *(const float4*)(in + i + 4);
    ushort_t o[8] = {f2b(a.x), f2b(a.y), f2b(a.z), f2b(a.w),
                     f2b(b.x), f2b(b.y), f2b(b.z), f2b(b.w)};
    *(int4*)(abuf + (size_t)row * 512 + 256 + col) = *(const int4*)o;
}

// W1l|W1r -> wc1[256,512], W2l|W2r -> wc2[256,512]
__global__ void cast_w_kernel(const float* __restrict__ w1l, const float* __restrict__ w1r,
                              const float* __restrict__ w2l, const float* __restrict__ w2r,
                              ushort_t* __restrict__ wc1, ushort_t* __restrict__ wc2) {
    int i = (blockIdx.x * 256 + threadIdx.x) * 8;   // 0 .. 4*65536
    int which = i >> 16;            // 0=W1l 1=W1r 2=W2l 3=W2r
    int o = i & 65535;
    int row = o >> 8, col = o & 255;
    const float* src = (which == 0) ? w1l : (which == 1) ? w1r
                      : (which == 2) ? w2l : w2r;
    ushort_t* dst = ((which < 2) ? wc1 : wc2) + (size_t)row * 512 + (which & 1) * 256 + col;
    float4 a = *(const float4*)(src + o);
    float4 b = *(const float4*)(src + o + 4);
    ushort_t ov[8] = {f2b(a.x), f2b(a.y), f2b(a.z), f2b(a.w),
                      f2b(b.x), f2b(b.y), f2b(b.z), f2b(b.w)};
    *(int4*)dst = *(const int4*)ov;
}

// ---------------- CSR build ----------------

__global__ void count_kernel(const int* __restrict__ ei, int* __restrict__ cnt, int E) {
    int e = blockIdx.x * 256 + threadIdx.x;
    if (e < E) atomicAdd(&cnt[ei[E + e]], 1);   // dst row is second row
}

// Stage 1: per-block (2048 elems) sums.
__global__ __launch_bounds__(256) void scan_partial_kernel(const int* __restrict__ cnt,
                                                           int* __restrict__ part, int n) {
    __shared__ int ws[4];
    int tid = threadIdx.x;
    int wave = tid >> 6, lane = tid & 63;
    int i0 = blockIdx.x * 2048 + tid * 8;
    int sum = 0;
    if (i0 + 8 <= n) {
        int4 a = *(const int4*)(cnt + i0);
        int4 b = *(const int4*)(cnt + i0 + 4);
        sum = a.x + a.y + a.z + a.w + b.x + b.y + b.z + b.w;
    } else {
        for (int j = i0; j < n; j++) sum += cnt[j];
    }
    #pragma unroll
    for (int off = 1; off < 64; off <<= 1) sum += __shfl_xor(sum, off);
    if (lane == 0) ws[wave] = sum;
    __syncthreads();
    if (tid == 0) part[blockIdx.x] = ws[0] + ws[1] + ws[2] + ws[3];
}

// Stage 2: exclusive scan of partials (single wave; nb <= 64).
__global__ void scan_partials2_kernel(int* __restrict__ part, int nb) {
    int lane = threadIdx.x;
    int v = (lane < nb) ? part[lane] : 0;
    int orig = v;
    #pragma unroll
    for (int off = 1; off < 64; off <<= 1) {
        int t = __shfl_up(v, off);
        if (lane >= off) v += t;
    }
    if (lane < nb) part[lane] = v - orig;   // exclusive base
}

// Stage 3: local rescan + base -> offs/cursor. offs[n] = E (degree sum).
__global__ __launch_bounds__(256) void scan_final_kernel(const int* __restrict__ cnt,
                                                         const int* __restrict__ part,
                                                         int* __restrict__ offs,
                                                         int* __restrict__ cursor,
                                                         int n, int E) {
    __shared__ int wt[4];
    int tid = threadIdx.x;
    int wave = tid >> 6, lane = tid & 63;
    int i0 = blockIdx.x * 2048 + tid * 8;
    int v[8], s[8];
    int run = 0;
    if (i0 + 8 <= n) {
        int4 a = *(const int4*)(cnt + i0);
        int4 b = *(const int4*)(cnt + i0 + 4);
        v[0] = a.x; v[1] = a.y; v[2] = a.z; v[3] = a.w;
        v[4] = b.x; v[5] = b.y; v[6] = b.z; v[7] = b.w;
    } else {
        #pragma unroll
        for (int j = 0; j < 8; j++) v[j] = (i0 + j < n) ? cnt[i0 + j] : 0;
    }
    #pragma unroll
    for (int j = 0; j < 8; j++) { run += v[j]; s[j] = run; }
    int tsum = run;
    int incl = tsum;
    #pragma unroll
    for (int off = 1; off < 64; off <<= 1) {
        int t = __shfl_up(incl, off);
        if (lane >= off) incl += t;
    }
    if (lane == 63) wt[wave] = incl;
    __syncthreads();
    int woff = 0;
    for (int w = 0; w < wave; w++) woff += wt[w];
    int texcl = part[blockIdx.x] + woff + (incl - tsum);
    #pragma unroll
    for (int j = 0; j < 8; j++) {
        int idx = i0 + j;
        if (idx < n) {
            int e = texcl + s[j] - v[j];
            offs[idx] = e;
            cursor[idx] = e;
        }
    }
    if (blockIdx.x == 0 && tid == 0) offs[n] = E;
}

__global__ void fill_kernel(const int* __restrict__ ei, int* __restrict__ cursor,
                            int* __restrict__ csr, int E) {
    int e = blockIdx.x * 256 + threadIdx.x;
    if (e < E) {
        int s = ei[e];
        int d = ei[E + e];
        int p = atomicAdd(&cursor[d], 1);
        csr[p] = s;
    }
}

// ---------------- mean aggregation (gather, wave-per-node) ----------------
// One 64-lane wave per node. Lanes 0-31 handle even neighbors, 32-63 odd
// (same dims via lane&31). Uniform trip count; unroll-4 => 8 neighbors /
// 4 dwordx4 in flight. Halves combined with __shfl_xor(32) at the end.

static __device__ __forceinline__ void add8(float* acc, int4 v) {
    const unsigned* u = (const unsigned*)&v;
    #pragma unroll
    for (int j = 0; j < 4; j++) {
        acc[2 * j]     += __uint_as_float(u[j] << 16);
        acc[2 * j + 1] += __uint_as_float(u[j] & 0xffff0000u);
    }
}

__global__ __launch_bounds__(256) void agg_kernel(const ushort_t* __restrict__ X,
                                                  const int* __restrict__ csr,
                                                  const int* __restrict__ offs,
                                                  ushort_t* __restrict__ mean, int N) {
    int wv = threadIdx.x >> 6;          // wave in block: node index
    int lane = threadIdx.x & 63;
    int half = lane >> 5;               // 0: even neighbors, 1: odd
    int c = lane & 31;                  // dim chunk (8 bf16)
    int node = blockIdx.x * 4 + wv;
    if (node >= N) return;
    int beg = offs[node], end = offs[node + 1];

    float acc[8];
    #pragma unroll
    for (int j = 0; j < 8; j++) acc[j] = 0.f;

    const ushort_t* base = X + (size_t)c * 8;
    int i = beg;
    for (; i + 8 <= end; i += 8) {
        int s0 = csr[i + half];
        int s1 = csr[i + 2 + half];
        int s2 = csr[i + 4 + half];
        int s3 = csr[i + 6 + half];
        int4 v0 = *(const int4*)(base + (size_t)s0 * 512);
        int4 v1 = *(const int4*)(base + (size_t)s1 * 512);
        int4 v2 = *(const int4*)(base + (size_t)s2 * 512);
        int4 v3 = *(const int4*)(base + (size_t)s3 * 512);
        add8(acc, v0); add8(acc, v1); add8(acc, v2); add8(acc, v3);
    }
    for (; i + 2 <= end; i += 2) {
        int s0 = csr[i + half];
        int4 v0 = *(const int4*)(base + (size_t)s0 * 512);
        add8(acc, v0);
    }
    if (i < end && half == 0) {
        int s0 = csr[i];
        int4 v0 = *(const int4*)(base + (size_t)s0 * 512);
        add8(acc, v0);
    }

    // combine the two halves (lane <-> lane^32 hold the same dims)
    #pragma unroll
    for (int j = 0; j < 8; j++) acc[j] += __shfl_xor(acc[j], 32);

    if (half == 0) {
        float scale = 1.f / fmaxf((float)(end - beg), 1.f);
        ushort_t o[8];
        #pragma unroll
        for (int j = 0; j < 8; j++) o[j] = f2b(acc[j] * scale);
        *(int4*)(mean + (size_t)node * 512 + c * 8) = *(const int4*)o;
    }
}

// ---------------- fused GEMM + bias + L2 norm (+relu) ----------------
// C[64 rows x 256 cols] per block. A = abuf[N,512], W = wc[256,512].
// BK=64, 8 K-iters. global_load_lds staging, XOR-swizzled 16B chunks.

__global__ __launch_bounds__(256, 3) void gemm_norm_kernel(
        const ushort_t* __restrict__ abuf,  // [N,512] bf16
        const ushort_t* __restrict__ W,     // [256,512] bf16
        const float*    __restrict__ bias,  // [256] fp32
        ushort_t* __restrict__ outb,        // bf16 out base (pre-offset), or null
        float*    __restrict__ outf,        // fp32 out, or null
        int ostride,                        // out row stride (elements)
        int N, int relu) {
    __shared__ union {
        struct {
            ushort_t As[64 * 64];    // 8 KB
            ushort_t Bs[256 * 64];   // 32 KB
        } s;
        ushort_t ebuf[64 * 264];     // 33.8 KB epilogue transpose buffer
    } u;
    __shared__ float rowsq[64];

    int tid = threadIdx.x;
    int wave = tid >> 6, lane = tid & 63;
    int quad = lane >> 4, m16 = lane & 15;
    int swz = m16 & 7;
    int rowbase = blockIdx.x * 64;

    if (tid < 64) rowsq[tid] = 0.f;

    f32x4 acc[4][4];
    #pragma unroll
    for (int i = 0; i < 4; i++)
        #pragma unroll
        for (int j = 0; j < 4; j++)
            acc[i][j] = (f32x4){0.f, 0.f, 0.f, 0.f};

    const ushort_t* Ag = abuf + (size_t)rowbase * 512;

    for (int ki = 0; ki < 8; ki++) {
        int kb = ki * 64;
        __syncthreads();   // previous iter's LDS reads complete
        #pragma unroll
        for (int t = 0; t < 2; t++) {
            int instr = wave * 2 + t;
            int flat = instr * 64 + lane;
            int row = flat >> 3, cc = flat & 7;
            int ccg = cc ^ (row & 7);
            load16(Ag + (size_t)row * 512 + kb + ccg * 8, &u.s.As[instr * 512]);
        }
        #pragma unroll
        for (int t = 0; t < 8; t++) {
            int instr = wave * 8 + t;
            int flat = instr * 64 + lane;
            int row = flat >> 3, cc = flat & 7;
            int ccg = cc ^ (row & 7);
            load16(W + (size_t)row * 512 + kb + ccg * 8, &u.s.Bs[instr * 512]);
        }
        __syncthreads();   // vmcnt(0) drain + barrier: tiles visible

        #pragma unroll
        for (int ks = 0; ks < 2; ks++) {
            int cbase = ks * 4 + quad;
            bf16x8 af[4], bfr[4];
            #pragma unroll
            for (int rt = 0; rt < 4; rt++) {
                int r = rt * 16 + m16;
                af[rt] = *(const bf16x8*)&u.s.As[r * 64 + (cbase ^ swz) * 8];
            }
            #pragma unroll
            for (int ct = 0; ct < 4; ct++) {
                int r = wave * 64 + ct * 16 + m16;
                bfr[ct] = *(const bf16x8*)&u.s.Bs[r * 64 + (cbase ^ swz) * 8];
            }
            #pragma unroll
            for (int rt = 0; rt < 4; rt++)
                #pragma unroll
                for (int ct = 0; ct < 4; ct++)
                    acc[rt][ct] = __builtin_amdgcn_mfma_f32_16x16x32_bf16(
                        af[rt], bfr[ct], acc[rt][ct], 0, 0, 0);
        }
    }

    // bias + per-row sum of squares (C/D layout: col=m16, row=quad*4+reg)
    float bvals[4];
    #pragma unroll
    for (int ct = 0; ct < 4; ct++)
        bvals[ct] = bias[wave * 64 + ct * 16 + m16];
    #pragma unroll
    for (int rt = 0; rt < 4; rt++) {
        #pragma unroll
        for (int reg = 0; reg < 4; reg++) {
            float s = 0.f;
            #pragma unroll
            for (int ct = 0; ct < 4; ct++) {
                float v = acc[rt][ct][reg] + bvals[ct];
                acc[rt][ct][reg] = v;
                s += v * v;
            }
            #pragma unroll
            for (int off = 1; off < 16; off <<= 1)
                s += __shfl_xor(s, off);
            if (m16 == 0)
                atomicAdd(&rowsq[rt * 16 + quad * 4 + reg], s);
        }
    }
    __syncthreads();   // rowsq complete; As/Bs reads done -> ebuf reuse safe

    // normalized values -> ebuf (bf16), then coalesced readback
    #pragma unroll
    for (int rt = 0; rt < 4; rt++) {
        #pragma unroll
        for (int reg = 0; reg < 4; reg++) {
            int r = rt * 16 + quad * 4 + reg;
            float inv = 1.f / fmaxf(sqrtf(rowsq[r]), 1e-12f);
            #pragma unroll
            for (int ct = 0; ct < 4; ct++) {
                float v = acc[rt][ct][reg] * inv;
                if (relu) v = fmaxf(v, 0.f);
                int col = wave * 64 + ct * 16 + m16;
                u.ebuf[r * 264 + col] = f2b(v);
            }
        }
    }
    __syncthreads();

    #pragma unroll
    for (int j = 0; j < 8; j++) {
        int flat = j * 256 + tid;          // 2048 chunks = 64 rows x 32
        int row = flat >> 5, cc = flat & 31;
        int gr = rowbase + row;
        if (gr < N) {
            bf16x8 v = *(const bf16x8*)&u.ebuf[row * 264 + cc * 8];
            if (outf) {
                float4 f0, f1;
                f0.x = b2f((ushort_t)v[0]); f0.y = b2f((ushort_t)v[1]);
                f0.z = b2f((ushort_t)v[2]); f0.w = b2f((ushort_t)v[3]);
                f1.x = b2f((ushort_t)v[4]); f1.y = b2f((ushort_t)v[5]);
                f1.z = b2f((ushort_t)v[6]); f1.w = b2f((ushort_t)v[7]);
                float* p = outf + (size_t)gr * ostride + cc * 8;
                *(float4*)p = f0;
                *(float4*)(p + 4) = f1;
            } else {
                *(bf16x8*)(outb + (size_t)gr * ostride + cc * 8) = v;
            }
        }
    }
}

// ---------------- launch ----------------

static inline size_t align_up(size_t x, size_t a) { return (x + a - 1) & ~(a - 1); }

extern "C" void kernel_launch(void* const* d_in, const int* in_sizes, int n_in,
                              void* d_out, int out_size, void* d_ws, size_t ws_size,
                              hipStream_t stream) {
    const float* x   = (const float*)d_in[0];
    const int*   ei  = (const int*)d_in[1];
    const float* W1l = (const float*)d_in[2];
    const float* b1l = (const float*)d_in[3];
    const float* W1r = (const float*)d_in[4];
    const float* W2l = (const float*)d_in[5];
    const float* b2l = (const float*)d_in[6];
    const float* W2r = (const float*)d_in[7];

    int N = in_sizes[0] / DD;
    int E = in_sizes[1] / 2;

    char* ws = (char*)d_ws;
    size_t off = 0;
    int* cnt = (int*)(ws + off);      off = align_up(off + (size_t)N * 4, 256);
    int* offs = (int*)(ws + off);     off = align_up(off + (size_t)(N + 1) * 4, 256);
    int* cursor = (int*)(ws + off);   off = align_up(off + (size_t)N * 4, 256);
    int* part = (int*)(ws + off);     off = align_up(off + (size_t)64 * 4, 256);
    int* csr = (int*)(ws + off);      off = align_up(off + (size_t)E * 4, 256);
    ushort_t* abuf = (ushort_t*)(ws + off);  off = align_up(off + (size_t)N * 512 * 2, 256);
    // gemm A-tile overreads up to 48 rows past N: wc1/wc2 (512KB) provide slack
    ushort_t* wc1 = (ushort_t*)(ws + off);   off = align_up(off + (size_t)256 * 512 * 2, 256);
    ushort_t* wc2 = (ushort_t*)(ws + off);   off = align_up(off + (size_t)256 * 512 * 2, 256);

    hipMemsetAsync(cnt, 0, (size_t)N * 4, stream);

    int xe = N * DD;
    cast_x_kernel<<<(xe / 8 + 255) / 256, 256, 0, stream>>>(x, abuf, xe);
    cast_w_kernel<<<(4 * DD * DD / 8) / 256, 256, 0, stream>>>(W1l, W1r, W2l, W2r,
                                                               wc1, wc2);

    int eb = (E + 255) / 256;
    count_kernel<<<eb, 256, 0, stream>>>(ei, cnt, E);
    int nb = (N + 2047) / 2048;   // <= 64 for N <= 131072
    scan_partial_kernel<<<nb, 256, 0, stream>>>(cnt, part, N);
    scan_partials2_kernel<<<1, 64, 0, stream>>>(part, nb);
    scan_final_kernel<<<nb, 256, 0, stream>>>(cnt, part, offs, cursor, N, E);
    fill_kernel<<<eb, 256, 0, stream>>>(ei, cursor, csr, E);

    int gb = (N + 63) / 64;
    int ab = (N + 3) / 4;   // wave-per-node, 4 nodes/block

    // layer 1: agg x -> abuf[:,0:256]; gemm -> h into abuf[:,256:512] (bf16)
    agg_kernel<<<ab, 256, 0, stream>>>(abuf + 256, csr, offs, abuf, N);
    gemm_norm_kernel<<<gb, 256, 0, stream>>>(abuf, wc1, b1l,
                                             abuf + 256, (float*)nullptr, 512, N, 1);

    // layer 2: agg h -> abuf[:,0:256]; gemm -> d_out (fp32)
    agg_kernel<<<ab, 256, 0, stream>>>(abuf + 256, csr, offs, abuf, N);
    gemm_norm_kernel<<<gb, 256, 0, stream>>>(abuf, wc2, b2l,
                                             (ushort_t*)nullptr, (float*)d_out, DD, N, 0);
}

// Round 7
// 365.181 us; speedup vs baseline: 1.0758x; 1.0758x over previous
//
#include <hip/hip_runtime.h>
#include <hip/hip_bf16.h>

// SAGE 2-layer: N nodes, E edges, D=256. FP32 inputs, bf16 MFMA pipeline.
// abuf[N,512] = [mean | x] (layer1) then [mean2 | h] (layer2, in place).
// Combined weights Wc[256 out, 512 k].
//
// R6: agg is at its structural floor (~54us: FETCH 174MB == compulsory
// cross-XCD duplication 8 x 43k rows x 512B; fabric-BW-bound, extra MLP
// was neutral). This round attacks the invisible 280us: gemm -> 128x256
// tile / 512 thr (halves W redundancy, 2x MFMA per staged byte), and
// dispatch fusion 13 -> 9 (prep = count+cast_x+cast_w; partial-scan
// inlined into scan_final).

#define DD 256

typedef unsigned short ushort_t;
using bf16x8 = __attribute__((ext_vector_type(8))) short;
using f32x4  = __attribute__((ext_vector_type(4))) float;

static __device__ __forceinline__ float b2f(ushort_t u) {
    __hip_bfloat16 h = *reinterpret_cast<__hip_bfloat16*>(&u);
    return __bfloat162float(h);
}
static __device__ __forceinline__ ushort_t f2b(float f) {
    __hip_bfloat16 h = __float2bfloat16(f);
    return *reinterpret_cast<ushort_t*>(&h);
}

static __device__ __forceinline__ void load16(const ushort_t* g, ushort_t* l) {
    __builtin_amdgcn_global_load_lds(
        (const __attribute__((address_space(1))) unsigned*)(g),
        (__attribute__((address_space(3))) unsigned*)(l),
        16, 0, 0);
}

// ---------------- fused prep: count + cast_x + cast_w ----------------
// grid = eb (count) | cxb (cast x) | cwb (cast W). All independent.

__global__ __launch_bounds__(256) void prep_kernel(
        const int* __restrict__ ei, int* __restrict__ cnt, int E, int eb,
        const float* __restrict__ x, ushort_t* __restrict__ abuf, int xe, int cxb,
        const float* __restrict__ w1l, const float* __restrict__ w1r,
        const float* __restrict__ w2l, const float* __restrict__ w2r,
        ushort_t* __restrict__ wc1, ushort_t* __restrict__ wc2) {
    int b = blockIdx.x;
    if (b < eb) {
        int e = b * 256 + threadIdx.x;
        if (e < E) atomicAdd(&cnt[ei[E + e]], 1);   // dst row = second row
        return;
    }
    b -= eb;
    if (b < cxb) {
        int i = (b * 256 + threadIdx.x) * 8;
        if (i + 8 > xe) return;
        int row = i >> 8, col = i & 255;
        float4 a = *(const float4*)(x + i);
        float4 c = *(const float4*)(x + i + 4);
        ushort_t o[8] = {f2b(a.x), f2b(a.y), f2b(a.z), f2b(a.w),
                         f2b(c.x), f2b(c.y), f2b(c.z), f2b(c.w)};
        *(int4*)(abuf + (size_t)row * 512 + 256 + col) = *(const int4*)o;
        return;
    }
    b -= cxb;
    {
        int i = (b * 256 + threadIdx.x) * 8;        // 0 .. 4*65536
        int which = i >> 16;                        // 0=W1l 1=W1r 2=W2l 3=W2r
        int o = i & 65535;
        int row = o >> 8, col = o & 255;
        const float* src = (which == 0) ? w1l : (which == 1) ? w1r
                          : (which == 2) ? w2l : w2r;
        ushort_t* dst = ((which < 2) ? wc1 : wc2)
                        + (size_t)row * 512 + (which & 1) * 256 + col;
        float4 a = *(const float4*)(src + o);
        float4 c = *(const float4*)(src + o + 4);
        ushort_t ov[8] = {f2b(a.x), f2b(a.y), f2b(a.z), f2b(a.w),
                          f2b(c.x), f2b(c.y), f2b(c.z), f2b(c.w)};
        *(int4*)dst = *(const int4*)ov;
    }
}

// ---------------- scan ----------------

// Stage 1: per-block (2048 elems) sums.
__global__ __launch_bounds__(256) void scan_partial_kernel(const int* __restrict__ cnt,
                                                           int* __restrict__ part, int n) {
    __shared__ int ws[4];
    int tid = threadIdx.x;
    int wave = tid >> 6, lane = tid & 63;
    int i0 = blockIdx.x * 2048 + tid * 8;
    int sum = 0;
    if (i0 + 8 <= n) {
        int4 a = *(const int4*)(cnt + i0);
        int4 b = *(const int4*)(cnt + i0 + 4);
        sum = a.x + a.y + a.z + a.w + b.x + b.y + b.z + b.w;
    } else {
        for (int j = i0; j < n; j++) sum += cnt[j];
    }
    #pragma unroll
    for (int off = 1; off < 64; off <<= 1) sum += __shfl_xor(sum, off);
    if (lane == 0) ws[wave] = sum;
    __syncthreads();
    if (tid == 0) part[blockIdx.x] = ws[0] + ws[1] + ws[2] + ws[3];
}

// Stage 2: local rescan + inline scan of partials (nb <= 64) -> offs/cursor.
__global__ __launch_bounds__(256) void scan_final_kernel(const int* __restrict__ cnt,
                                                         const int* __restrict__ part,
                                                         int* __restrict__ offs,
                                                         int* __restrict__ cursor,
                                                         int n, int E, int nb) {
    __shared__ int wt[4];
    __shared__ int sbase;
    int tid = threadIdx.x;
    int wave = tid >> 6, lane = tid & 63;
    // wave 0: redundant exclusive scan of block partials, pick ours
    if (tid < 64) {
        int pv = (tid < nb) ? part[tid] : 0;
        int incl = pv;
        #pragma unroll
        for (int off = 1; off < 64; off <<= 1) {
            int t = __shfl_up(incl, off);
            if (tid >= off) incl += t;
        }
        if (tid == (int)blockIdx.x) sbase = incl - pv;
    }
    int i0 = blockIdx.x * 2048 + tid * 8;
    int v[8], s[8];
    int run = 0;
    if (i0 + 8 <= n) {
        int4 a = *(const int4*)(cnt + i0);
        int4 b = *(const int4*)(cnt + i0 + 4);
        v[0] = a.x; v[1] = a.y; v[2] = a.z; v[3] = a.w;
        v[4] = b.x; v[5] = b.y; v[6] = b.z; v[7] = b.w;
    } else {
        #pragma unroll
        for (int j = 0; j < 8; j++) v[j] = (i0 + j < n) ? cnt[i0 + j] : 0;
    }
    #pragma unroll
    for (int j = 0; j < 8; j++) { run += v[j]; s[j] = run; }
    int tsum = run;
    int incl = tsum;
    #pragma unroll
    for (int off = 1; off < 64; off <<= 1) {
        int t = __shfl_up(incl, off);
        if (lane >= off) incl += t;
    }
    if (lane == 63) wt[wave] = incl;
    __syncthreads();
    int woff = 0;
    for (int w = 0; w < wave; w++) woff += wt[w];
    int texcl = sbase + woff + (incl - tsum);
    #pragma unroll
    for (int j = 0; j < 8; j++) {
        int idx = i0 + j;
        if (idx < n) {
            int e = texcl + s[j] - v[j];
            offs[idx] = e;
            cursor[idx] = e;
        }
    }
    if (blockIdx.x == 0 && tid == 0) offs[n] = E;
}

__global__ void fill_kernel(const int* __restrict__ ei, int* __restrict__ cursor,
                            int* __restrict__ csr, int E) {
    int e = blockIdx.x * 256 + threadIdx.x;
    if (e < E) {
        int s = ei[e];
        int d = ei[E + e];
        int p = atomicAdd(&cursor[d], 1);
        csr[p] = s;
    }
}

// ---------------- mean aggregation (gather, wave-per-node) ----------------

static __device__ __forceinline__ void add8(float* acc, int4 v) {
    const unsigned* u = (const unsigned*)&v;
    #pragma unroll
    for (int j = 0; j < 4; j++) {
        acc[2 * j]     += __uint_as_float(u[j] << 16);
        acc[2 * j + 1] += __uint_as_float(u[j] & 0xffff0000u);
    }
}

__global__ __launch_bounds__(256) void agg_kernel(const ushort_t* __restrict__ X,
                                                  const int* __restrict__ csr,
                                                  const int* __restrict__ offs,
                                                  ushort_t* __restrict__ mean, int N) {
    int wv = threadIdx.x >> 6;
    int lane = threadIdx.x & 63;
    int half = lane >> 5;
    int c = lane & 31;
    int node = blockIdx.x * 4 + wv;
    if (node >= N) return;
    int beg = offs[node], end = offs[node + 1];

    float acc[8];
    #pragma unroll
    for (int j = 0; j < 8; j++) acc[j] = 0.f;

    const ushort_t* base = X + (size_t)c * 8;
    int i = beg;
    for (; i + 8 <= end; i += 8) {
        int s0 = csr[i + half];
        int s1 = csr[i + 2 + half];
        int s2 = csr[i + 4 + half];
        int s3 = csr[i + 6 + half];
        int4 v0 = *(const int4*)(base + (size_t)s0 * 512);
        int4 v1 = *(const int4*)(base + (size_t)s1 * 512);
        int4 v2 = *(const int4*)(base + (size_t)s2 * 512);
        int4 v3 = *(const int4*)(base + (size_t)s3 * 512);
        add8(acc, v0); add8(acc, v1); add8(acc, v2); add8(acc, v3);
    }
    for (; i + 2 <= end; i += 2) {
        int s0 = csr[i + half];
        int4 v0 = *(const int4*)(base + (size_t)s0 * 512);
        add8(acc, v0);
    }
    if (i < end && half == 0) {
        int s0 = csr[i];
        int4 v0 = *(const int4*)(base + (size_t)s0 * 512);
        add8(acc, v0);
    }

    #pragma unroll
    for (int j = 0; j < 8; j++) acc[j] += __shfl_xor(acc[j], 32);

    if (half == 0) {
        float scale = 1.f / fmaxf((float)(end - beg), 1.f);
        ushort_t o[8];
        #pragma unroll
        for (int j = 0; j < 8; j++) o[j] = f2b(acc[j] * scale);
        *(int4*)(mean + (size_t)node * 512 + c * 8) = *(const int4*)o;
    }
}

// ---------------- fused GEMM + bias + L2 norm (+relu) ----------------
// C[128 rows x 256 cols] per block, 512 threads / 8 waves. Wave w owns
// rows (w>>2)*64 .. +64, cols (w&3)*64 .. +64 (4x4 frags of 16x16x32).
// BK=64, 8 K-iters, global_load_lds(16B) with XOR-swizzled chunks.
// Epilogue: two 64-row passes through ebuf (LDS) -> coalesced stores.

__global__ __launch_bounds__(512, 4) void gemm_norm_kernel(
        const ushort_t* __restrict__ abuf,  // [N,512] bf16
        const ushort_t* __restrict__ W,     // [256,512] bf16
        const float*    __restrict__ bias,  // [256] fp32
        ushort_t* __restrict__ outb,        // bf16 out base (pre-offset), or null
        float*    __restrict__ outf,        // fp32 out, or null
        int ostride,                        // out row stride (elements)
        int N, int relu) {
    __shared__ union {
        struct {
            ushort_t As[128 * 64];   // 16 KB
            ushort_t Bs[256 * 64];   // 32 KB
        } s;
        ushort_t ebuf[64 * 264];     // 33.8 KB (one 64-row epilogue pass)
    } u;
    __shared__ float rowsq[128];

    int tid = threadIdx.x;
    int wave = tid >> 6, lane = tid & 63;
    int quad = lane >> 4, m16 = lane & 15;
    int swz = m16 & 7;
    int rowhalf = wave >> 2;            // 0 or 1
    int colq = wave & 3;                // 0..3
    int rowbase = blockIdx.x * 128;

    if (tid < 128) rowsq[tid] = 0.f;

    f32x4 acc[4][4];
    #pragma unroll
    for (int i = 0; i < 4; i++)
        #pragma unroll
        for (int j = 0; j < 4; j++)
            acc[i][j] = (f32x4){0.f, 0.f, 0.f, 0.f};

    const ushort_t* Ag = abuf + (size_t)rowbase * 512;

    for (int ki = 0; ki < 8; ki++) {
        int kb = ki * 64;
        __syncthreads();   // previous iter's LDS reads complete
        // A tile: 128 rows x 64 k = 16 DMA instrs, 2 per wave
        #pragma unroll
        for (int t = 0; t < 2; t++) {
            int instr = wave * 2 + t;
            int flat = instr * 64 + lane;
            int row = flat >> 3, cc = flat & 7;
            int ccg = cc ^ (row & 7);
            load16(Ag + (size_t)row * 512 + kb + ccg * 8, &u.s.As[instr * 512]);
        }
        // B tile: 256 rows x 64 k = 32 DMA instrs, 4 per wave
        #pragma unroll
        for (int t = 0; t < 4; t++) {
            int instr = wave * 4 + t;
            int flat = instr * 64 + lane;
            int row = flat >> 3, cc = flat & 7;
            int ccg = cc ^ (row & 7);
            load16(W + (size_t)row * 512 + kb + ccg * 8, &u.s.Bs[instr * 512]);
        }
        __syncthreads();   // vmcnt(0) drain + barrier: tiles visible

        #pragma unroll
        for (int ks = 0; ks < 2; ks++) {
            int cbase = ks * 4 + quad;
            bf16x8 af[4], bfr[4];
            #pragma unroll
            for (int rt = 0; rt < 4; rt++) {
                int r = rowhalf * 64 + rt * 16 + m16;
                af[rt] = *(const bf16x8*)&u.s.As[r * 64 + (cbase ^ swz) * 8];
            }
            #pragma unroll
            for (int ct = 0; ct < 4; ct++) {
                int r = colq * 64 + ct * 16 + m16;
                bfr[ct] = *(const bf16x8*)&u.s.Bs[r * 64 + (cbase ^ swz) * 8];
            }
            #pragma unroll
            for (int rt = 0; rt < 4; rt++)
                #pragma unroll
                for (int ct = 0; ct < 4; ct++)
                    acc[rt][ct] = __builtin_amdgcn_mfma_f32_16x16x32_bf16(
                        af[rt], bfr[ct], acc[rt][ct], 0, 0, 0);
        }
    }

    // bias + per-row sum of squares (C/D layout: col=m16, row=quad*4+reg)
    float bvals[4];
    #pragma unroll
    for (int ct = 0; ct < 4; ct++)
        bvals[ct] = bias[colq * 64 + ct * 16 + m16];
    #pragma unroll
    for (int rt = 0; rt < 4; rt++) {
        #pragma unroll
        for (int reg = 0; reg < 4; reg++) {
            float s = 0.f;
            #pragma unroll
            for (int ct = 0; ct < 4; ct++) {
                float v = acc[rt][ct][reg] + bvals[ct];
                acc[rt][ct][reg] = v;
                s += v * v;
            }
            #pragma unroll
            for (int off = 1; off < 16; off <<= 1)
                s += __shfl_xor(s, off);
            if (m16 == 0)
                atomicAdd(&rowsq[rowhalf * 64 + rt * 16 + quad * 4 + reg], s);
        }
    }
    __syncthreads();   // rowsq complete; all As/Bs reads done -> ebuf safe

    #pragma unroll
    for (int p = 0; p < 2; p++) {
        if (rowhalf == p) {
            #pragma unroll
            for (int rt = 0; rt < 4; rt++) {
                #pragma unroll
                for (int reg = 0; reg < 4; reg++) {
                    int rl = rt * 16 + quad * 4 + reg;       // row within pass
                    float inv = 1.f / fmaxf(sqrtf(rowsq[p * 64 + rl]), 1e-12f);
                    #pragma unroll
                    for (int ct = 0; ct < 4; ct++) {
                        float v = acc[rt][ct][reg] * inv;
                        if (relu) v = fmaxf(v, 0.f);
                        int col = colq * 64 + ct * 16 + m16;
                        u.ebuf[rl * 264 + col] = f2b(v);
                    }
                }
            }
        }
        __syncthreads();
        #pragma unroll
        for (int j = 0; j < 4; j++) {
            int flat = j * 512 + tid;          // 2048 chunks = 64 rows x 32
            int row = flat >> 5, cc = flat & 31;
            int gr = rowbase + p * 64 + row;
            if (gr < N) {
                bf16x8 v = *(const bf16x8*)&u.ebuf[row * 264 + cc * 8];
                if (outf) {
                    float4 f0, f1;
                    f0.x = b2f((ushort_t)v[0]); f0.y = b2f((ushort_t)v[1]);
                    f0.z = b2f((ushort_t)v[2]); f0.w = b2f((ushort_t)v[3]);
                    f1.x = b2f((ushort_t)v[4]); f1.y = b2f((ushort_t)v[5]);
                    f1.z = b2f((ushort_t)v[6]); f1.w = b2f((ushort_t)v[7]);
                    float* ptr = outf + (size_t)gr * ostride + cc * 8;
                    *(float4*)ptr = f0;
                    *(float4*)(ptr + 4) = f1;
                } else {
                    *(bf16x8*)(outb + (size_t)gr * ostride + cc * 8) = v;
                }
            }
        }
        __syncthreads();   // ebuf reused by next pass
    }
}

// ---------------- launch ----------------

static inline size_t align_up(size_t x, size_t a) { return (x + a - 1) & ~(a - 1); }

extern "C" void kernel_launch(void* const* d_in, const int* in_sizes, int n_in,
                              void* d_out, int out_size, void* d_ws, size_t ws_size,
                              hipStream_t stream) {
    const float* x   = (const float*)d_in[0];
    const int*   ei  = (const int*)d_in[1];
    const float* W1l = (const float*)d_in[2];
    const float* b1l = (const float*)d_in[3];
    const float* W1r = (const float*)d_in[4];
    const float* W2l = (const float*)d_in[5];
    const float* b2l = (const float*)d_in[6];
    const float* W2r = (const float*)d_in[7];

    int N = in_sizes[0] / DD;
    int E = in_sizes[1] / 2;

    char* ws = (char*)d_ws;
    size_t off = 0;
    int* cnt = (int*)(ws + off);      off = align_up(off + (size_t)N * 4, 256);
    int* offs = (int*)(ws + off);     off = align_up(off + (size_t)(N + 1) * 4, 256);
    int* cursor = (int*)(ws + off);   off = align_up(off + (size_t)N * 4, 256);
    int* part = (int*)(ws + off);     off = align_up(off + (size_t)64 * 4, 256);
    int* csr = (int*)(ws + off);      off = align_up(off + (size_t)E * 4, 256);
    ushort_t* abuf = (ushort_t*)(ws + off);  off = align_up(off + (size_t)N * 512 * 2, 256);
    // gemm A-tile overreads up to 127 rows past N (128-row tiles):
    // wc1/wc2 (512KB) directly follow abuf and provide the slack.
    ushort_t* wc1 = (ushort_t*)(ws + off);   off = align_up(off + (size_t)256 * 512 * 2, 256);
    ushort_t* wc2 = (ushort_t*)(ws + off);   off = align_up(off + (size_t)256 * 512 * 2, 256);

    hipMemsetAsync(cnt, 0, (size_t)N * 4, stream);

    int xe = N * DD;
    int eb = (E + 255) / 256;
    int cxb = (xe / 8 + 255) / 256;
    int cwb = (4 * DD * DD / 8) / 256;
    prep_kernel<<<eb + cxb + cwb, 256, 0, stream>>>(ei, cnt, E, eb,
                                                    x, abuf, xe, cxb,
                                                    W1l, W1r, W2l, W2r, wc1, wc2);

    int nb = (N + 2047) / 2048;   // <= 64 for N <= 131072
    scan_partial_kernel<<<nb, 256, 0, stream>>>(cnt, part, N);
    scan_final_kernel<<<nb, 256, 0, stream>>>(cnt, part, offs, cursor, N, E, nb);
    fill_kernel<<<eb, 256, 0, stream>>>(ei, cursor, csr, E);

    int gb = (N + 127) / 128;
    int ab = (N + 3) / 4;

    // layer 1: agg x -> abuf[:,0:256]; gemm -> h into abuf[:,256:512] (bf16)
    agg_kernel<<<ab, 256, 0, stream>>>(abuf + 256, csr, offs, abuf, N);
    gemm_norm_kernel<<<gb, 512, 0, stream>>>(abuf, wc1, b1l,
                                             abuf + 256, (float*)nullptr, 512, N, 1);

    // layer 2: agg h -> abuf[:,0:256]; gemm -> d_out (fp32)
    agg_kernel<<<ab, 256, 0, stream>>>(abuf + 256, csr, offs, abuf, N);
    gemm_norm_kernel<<<gb, 512, 0, stream>>>(abuf, wc2, b2l,
                                             (ushort_t*)nullptr, (float*)d_out, DD, N, 0);
}

// Round 8
// 331.304 us; speedup vs baseline: 1.1858x; 1.1023x over previous
//
#include <hip/hip_runtime.h>
#include <hip/hip_bf16.h>

// SAGE 2-layer: N nodes, E edges, D=256. FP32 inputs, bf16 MFMA pipeline.
// abuf[N,512] = [mean | x] (layer1) then [mean2 | h] (layer2, in place).
// Combined weights Wc[256 out, 512 k].
//
// R7: fill_kernel was 60us — WRITE_SIZE 52MB = 800k x 64B partial-line
// writebacks (random 4B scatter, lines shared across XCDs never merge).
// Now a 2-pass counting sort: part_kernel buckets edges by dst>>7 into a
// csr-parallel stage[] (block-local LDS rank + one reserve atomic per
// bucket per block); group_kernel gives each bucket to ONE block (LDS
// cursors, csr window ~8KB, XCD-local -> full-line merged writebacks).

#define DD 256
#define NPB 128          // nodes per bucket (dst >> 7)

typedef unsigned short ushort_t;
using bf16x8 = __attribute__((ext_vector_type(8))) short;
using f32x4  = __attribute__((ext_vector_type(4))) float;

static __device__ __forceinline__ float b2f(ushort_t u) {
    __hip_bfloat16 h = *reinterpret_cast<__hip_bfloat16*>(&u);
    return __bfloat162float(h);
}
static __device__ __forceinline__ ushort_t f2b(float f) {
    __hip_bfloat16 h = __float2bfloat16(f);
    return *reinterpret_cast<ushort_t*>(&h);
}

static __device__ __forceinline__ void load16(const ushort_t* g, ushort_t* l) {
    __builtin_amdgcn_global_load_lds(
        (const __attribute__((address_space(1))) unsigned*)(g),
        (__attribute__((address_space(3))) unsigned*)(l),
        16, 0, 0);
}

// ---------------- fused prep: count + cast_x + cast_w ----------------

__global__ __launch_bounds__(256) void prep_kernel(
        const int* __restrict__ ei, int* __restrict__ cnt, int E, int eb,
        const float* __restrict__ x, ushort_t* __restrict__ abuf, int xe, int cxb,
        const float* __restrict__ w1l, const float* __restrict__ w1r,
        const float* __restrict__ w2l, const float* __restrict__ w2r,
        ushort_t* __restrict__ wc1, ushort_t* __restrict__ wc2) {
    int b = blockIdx.x;
    if (b < eb) {
        int e = b * 256 + threadIdx.x;
        if (e < E) atomicAdd(&cnt[ei[E + e]], 1);   // dst row = second row
        return;
    }
    b -= eb;
    if (b < cxb) {
        int i = (b * 256 + threadIdx.x) * 8;
        if (i + 8 > xe) return;
        int row = i >> 8, col = i & 255;
        float4 a = *(const float4*)(x + i);
        float4 c = *(const float4*)(x + i + 4);
        ushort_t o[8] = {f2b(a.x), f2b(a.y), f2b(a.z), f2b(a.w),
                         f2b(c.x), f2b(c.y), f2b(c.z), f2b(c.w)};
        *(int4*)(abuf + (size_t)row * 512 + 256 + col) = *(const int4*)o;
        return;
    }
    b -= cxb;
    {
        int i = (b * 256 + threadIdx.x) * 8;        // 0 .. 4*65536
        int which = i >> 16;                        // 0=W1l 1=W1r 2=W2l 3=W2r
        int o = i & 65535;
        int row = o >> 8, col = o & 255;
        const float* src = (which == 0) ? w1l : (which == 1) ? w1r
                          : (which == 2) ? w2l : w2r;
        ushort_t* dst = ((which < 2) ? wc1 : wc2)
                        + (size_t)row * 512 + (which & 1) * 256 + col;
        float4 a = *(const float4*)(src + o);
        float4 c = *(const float4*)(src + o + 4);
        ushort_t ov[8] = {f2b(a.x), f2b(a.y), f2b(a.z), f2b(a.w),
                          f2b(c.x), f2b(c.y), f2b(c.z), f2b(c.w)};
        *(int4*)dst = *(const int4*)ov;
    }
}

// ---------------- scan ----------------

__global__ __launch_bounds__(256) void scan_partial_kernel(const int* __restrict__ cnt,
                                                           int* __restrict__ part, int n) {
    __shared__ int ws[4];
    int tid = threadIdx.x;
    int wave = tid >> 6, lane = tid & 63;
    int i0 = blockIdx.x * 2048 + tid * 8;
    int sum = 0;
    if (i0 + 8 <= n) {
        int4 a = *(const int4*)(cnt + i0);
        int4 b = *(const int4*)(cnt + i0 + 4);
        sum = a.x + a.y + a.z + a.w + b.x + b.y + b.z + b.w;
    } else {
        for (int j = i0; j < n; j++) sum += cnt[j];
    }
    #pragma unroll
    for (int off = 1; off < 64; off <<= 1) sum += __shfl_xor(sum, off);
    if (lane == 0) ws[wave] = sum;
    __syncthreads();
    if (tid == 0) part[blockIdx.x] = ws[0] + ws[1] + ws[2] + ws[3];
}

// local rescan + inline partial-scan -> offs; seeds bcur[b]=offs[b*NPB].
__global__ __launch_bounds__(256) void scan_final_kernel(const int* __restrict__ cnt,
                                                         const int* __restrict__ part,
                                                         int* __restrict__ offs,
                                                         int* __restrict__ bcur,
                                                         int n, int E, int nb) {
    __shared__ int wt[4];
    __shared__ int sbase;
    int tid = threadIdx.x;
    int wave = tid >> 6, lane = tid & 63;
    if (tid < 64) {
        int pv = (tid < nb) ? part[tid] : 0;
        int incl = pv;
        #pragma unroll
        for (int off = 1; off < 64; off <<= 1) {
            int t = __shfl_up(incl, off);
            if (tid >= off) incl += t;
        }
        if (tid == (int)blockIdx.x) sbase = incl - pv;
    }
    int i0 = blockIdx.x * 2048 + tid * 8;
    int v[8], s[8];
    int run = 0;
    if (i0 + 8 <= n) {
        int4 a = *(const int4*)(cnt + i0);
        int4 b = *(const int4*)(cnt + i0 + 4);
        v[0] = a.x; v[1] = a.y; v[2] = a.z; v[3] = a.w;
        v[4] = b.x; v[5] = b.y; v[6] = b.z; v[7] = b.w;
    } else {
        #pragma unroll
        for (int j = 0; j < 8; j++) v[j] = (i0 + j < n) ? cnt[i0 + j] : 0;
    }
    #pragma unroll
    for (int j = 0; j < 8; j++) { run += v[j]; s[j] = run; }
    int tsum = run;
    int incl = tsum;
    #pragma unroll
    for (int off = 1; off < 64; off <<= 1) {
        int t = __shfl_up(incl, off);
        if (lane >= off) incl += t;
    }
    if (lane == 63) wt[wave] = incl;
    __syncthreads();
    int woff = 0;
    for (int w = 0; w < wave; w++) woff += wt[w];
    int texcl = sbase + woff + (incl - tsum);
    #pragma unroll
    for (int j = 0; j < 8; j++) {
        int idx = i0 + j;
        if (idx < n) {
            int e = texcl + s[j] - v[j];
            offs[idx] = e;
            if ((idx & (NPB - 1)) == 0) bcur[idx / NPB] = e;
        }
    }
    if (blockIdx.x == 0 && tid == 0) offs[n] = E;
}

// ---------------- CSR build: 2-pass counting sort ----------------

// Pass 1: partition edges into dst>>7 buckets; stage[] is csr-parallel.
__global__ __launch_bounds__(256) void part_kernel(const int* __restrict__ ei,
                                                   int* __restrict__ bcur,
                                                   int2* __restrict__ stage,
                                                   int E, int nbuck) {
    __shared__ int hist[512];
    __shared__ int gbase[512];
    int tid = threadIdx.x;
    for (int i = tid; i < nbuck; i += 256) hist[i] = 0;
    __syncthreads();
    int sv[8], dv[8], bk[8], rk[8];
    #pragma unroll
    for (int j = 0; j < 8; j++) {
        int e = blockIdx.x * 2048 + j * 256 + tid;
        if (e < E) {
            sv[j] = ei[e];
            dv[j] = ei[E + e];
            bk[j] = dv[j] / NPB;
            rk[j] = atomicAdd(&hist[bk[j]], 1);
        } else bk[j] = -1;
    }
    __syncthreads();
    for (int i = tid; i < nbuck; i += 256) {
        int h = hist[i];
        gbase[i] = h ? atomicAdd(&bcur[i], h) : 0;
    }
    __syncthreads();
    #pragma unroll
    for (int j = 0; j < 8; j++)
        if (bk[j] >= 0) {
            int p = gbase[bk[j]] + rk[j];
            stage[p] = make_int2(sv[j], dv[j]);
        }
}

// Pass 2: one block per bucket; exact per-node positions via LDS cursors;
// csr writes confined to one small XCD-local window -> merged writebacks.
__global__ __launch_bounds__(256) void group_kernel(const int2* __restrict__ stage,
                                                    const int* __restrict__ offs,
                                                    int* __restrict__ csr, int N) {
    __shared__ int lcur[NPB];
    int b = blockIdx.x;
    int lo = b * NPB;
    int hi = min(N, lo + NPB);
    int tid = threadIdx.x;
    if (tid < hi - lo) lcur[tid] = offs[lo + tid];
    __syncthreads();
    int base = offs[lo];
    int m = offs[hi] - base;
    for (int t = tid; t < m; t += 256) {
        int2 v = stage[base + t];
        int p = atomicAdd(&lcur[v.y - lo], 1);
        csr[p] = v.x;
    }
}

// ---------------- mean aggregation (gather, wave-per-node) ----------------

static __device__ __forceinline__ void add8(float* acc, int4 v) {
    const unsigned* u = (const unsigned*)&v;
    #pragma unroll
    for (int j = 0; j < 4; j++) {
        acc[2 * j]     += __uint_as_float(u[j] << 16);
        acc[2 * j + 1] += __uint_as_float(u[j] & 0xffff0000u);
    }
}

__global__ __launch_bounds__(256) void agg_kernel(const ushort_t* __restrict__ X,
                                                  const int* __restrict__ csr,
                                                  const int* __restrict__ offs,
                                                  ushort_t* __restrict__ mean, int N) {
    int wv = threadIdx.x >> 6;
    int lane = threadIdx.x & 63;
    int half = lane >> 5;
    int c = lane & 31;
    int node = blockIdx.x * 4 + wv;
    if (node >= N) return;
    int beg = offs[node], end = offs[node + 1];

    float acc[8];
    #pragma unroll
    for (int j = 0; j < 8; j++) acc[j] = 0.f;

    const ushort_t* base = X + (size_t)c * 8;
    int i = beg;
    for (; i + 8 <= end; i += 8) {
        int s0 = csr[i + half];
        int s1 = csr[i + 2 + half];
        int s2 = csr[i + 4 + half];
        int s3 = csr[i + 6 + half];
        int4 v0 = *(const int4*)(base + (size_t)s0 * 512);
        int4 v1 = *(const int4*)(base + (size_t)s1 * 512);
        int4 v2 = *(const int4*)(base + (size_t)s2 * 512);
        int4 v3 = *(const int4*)(base + (size_t)s3 * 512);
        add8(acc, v0); add8(acc, v1); add8(acc, v2); add8(acc, v3);
    }
    for (; i + 2 <= end; i += 2) {
        int s0 = csr[i + half];
        int4 v0 = *(const int4*)(base + (size_t)s0 * 512);
        add8(acc, v0);
    }
    if (i < end && half == 0) {
        int s0 = csr[i];
        int4 v0 = *(const int4*)(base + (size_t)s0 * 512);
        add8(acc, v0);
    }

    #pragma unroll
    for (int j = 0; j < 8; j++) acc[j] += __shfl_xor(acc[j], 32);

    if (half == 0) {
        float scale = 1.f / fmaxf((float)(end - beg), 1.f);
        ushort_t o[8];
        #pragma unroll
        for (int j = 0; j < 8; j++) o[j] = f2b(acc[j] * scale);
        *(int4*)(mean + (size_t)node * 512 + c * 8) = *(const int4*)o;
    }
}

// ---------------- fused GEMM + bias + L2 norm (+relu) ----------------
// C[128 x 256] per block, 512 threads / 8 waves. BK=64, 8 K-iters,
// global_load_lds(16B), XOR-swizzled chunks. 2-pass LDS-transpose epilogue.

__global__ __launch_bounds__(512, 4) void gemm_norm_kernel(
        const ushort_t* __restrict__ abuf,  // [N,512] bf16
        const ushort_t* __restrict__ W,     // [256,512] bf16
        const float*    __restrict__ bias,  // [256] fp32
        ushort_t* __restrict__ outb,        // bf16 out base (pre-offset), or null
        float*    __restrict__ outf,        // fp32 out, or null
        int ostride,                        // out row stride (elements)
        int N, int relu) {
    __shared__ union {
        struct {
            ushort_t As[128 * 64];   // 16 KB
            ushort_t Bs[256 * 64];   // 32 KB
        } s;
        ushort_t ebuf[64 * 264];     // 33.8 KB (one 64-row epilogue pass)
    } u;
    __shared__ float rowsq[128];

    int tid = threadIdx.x;
    int wave = tid >> 6, lane = tid & 63;
    int quad = lane >> 4, m16 = lane & 15;
    int swz = m16 & 7;
    int rowhalf = wave >> 2;            // 0 or 1
    int colq = wave & 3;                // 0..3
    int rowbase = blockIdx.x * 128;

    if (tid < 128) rowsq[tid] = 0.f;

    f32x4 acc[4][4];
    #pragma unroll
    for (int i = 0; i < 4; i++)
        #pragma unroll
        for (int j = 0; j < 4; j++)
            acc[i][j] = (f32x4){0.f, 0.f, 0.f, 0.f};

    const ushort_t* Ag = abuf + (size_t)rowbase * 512;

    for (int ki = 0; ki < 8; ki++) {
        int kb = ki * 64;
        __syncthreads();
        #pragma unroll
        for (int t = 0; t < 2; t++) {
            int instr = wave * 2 + t;
            int flat = instr * 64 + lane;
            int row = flat >> 3, cc = flat & 7;
            int ccg = cc ^ (row & 7);
            load16(Ag + (size_t)row * 512 + kb + ccg * 8, &u.s.As[instr * 512]);
        }
        #pragma unroll
        for (int t = 0; t < 4; t++) {
            int instr = wave * 4 + t;
            int flat = instr * 64 + lane;
            int row = flat >> 3, cc = flat & 7;
            int ccg = cc ^ (row & 7);
            load16(W + (size_t)row * 512 + kb + ccg * 8, &u.s.Bs[instr * 512]);
        }
        __syncthreads();

        #pragma unroll
        for (int ks = 0; ks < 2; ks++) {
            int cbase = ks * 4 + quad;
            bf16x8 af[4], bfr[4];
            #pragma unroll
            for (int rt = 0; rt < 4; rt++) {
                int r = rowhalf * 64 + rt * 16 + m16;
                af[rt] = *(const bf16x8*)&u.s.As[r * 64 + (cbase ^ swz) * 8];
            }
            #pragma unroll
            for (int ct = 0; ct < 4; ct++) {
                int r = colq * 64 + ct * 16 + m16;
                bfr[ct] = *(const bf16x8*)&u.s.Bs[r * 64 + (cbase ^ swz) * 8];
            }
            #pragma unroll
            for (int rt = 0; rt < 4; rt++)
                #pragma unroll
                for (int ct = 0; ct < 4; ct++)
                    acc[rt][ct] = __builtin_amdgcn_mfma_f32_16x16x32_bf16(
                        af[rt], bfr[ct], acc[rt][ct], 0, 0, 0);
        }
    }

    float bvals[4];
    #pragma unroll
    for (int ct = 0; ct < 4; ct++)
        bvals[ct] = bias[colq * 64 + ct * 16 + m16];
    #pragma unroll
    for (int rt = 0; rt < 4; rt++) {
        #pragma unroll
        for (int reg = 0; reg < 4; reg++) {
            float s = 0.f;
            #pragma unroll
            for (int ct = 0; ct < 4; ct++) {
                float v = acc[rt][ct][reg] + bvals[ct];
                acc[rt][ct][reg] = v;
                s += v * v;
            }
            #pragma unroll
            for (int off = 1; off < 16; off <<= 1)
                s += __shfl_xor(s, off);
            if (m16 == 0)
                atomicAdd(&rowsq[rowhalf * 64 + rt * 16 + quad * 4 + reg], s);
        }
    }
    __syncthreads();

    #pragma unroll
    for (int p = 0; p < 2; p++) {
        if (rowhalf == p) {
            #pragma unroll
            for (int rt = 0; rt < 4; rt++) {
                #pragma unroll
                for (int reg = 0; reg < 4; reg++) {
                    int rl = rt * 16 + quad * 4 + reg;
                    float inv = 1.f / fmaxf(sqrtf(rowsq[p * 64 + rl]), 1e-12f);
                    #pragma unroll
                    for (int ct = 0; ct < 4; ct++) {
                        float v = acc[rt][ct][reg] * inv;
                        if (relu) v = fmaxf(v, 0.f);
                        int col = colq * 64 + ct * 16 + m16;
                        u.ebuf[rl * 264 + col] = f2b(v);
                    }
                }
            }
        }
        __syncthreads();
        #pragma unroll
        for (int j = 0; j < 4; j++) {
            int flat = j * 512 + tid;
            int row = flat >> 5, cc = flat & 31;
            int gr = rowbase + p * 64 + row;
            if (gr < N) {
                bf16x8 v = *(const bf16x8*)&u.ebuf[row * 264 + cc * 8];
                if (outf) {
                    float4 f0, f1;
                    f0.x = b2f((ushort_t)v[0]); f0.y = b2f((ushort_t)v[1]);
                    f0.z = b2f((ushort_t)v[2]); f0.w = b2f((ushort_t)v[3]);
                    f1.x = b2f((ushort_t)v[4]); f1.y = b2f((ushort_t)v[5]);
                    f1.z = b2f((ushort_t)v[6]); f1.w = b2f((ushort_t)v[7]);
                    float* ptr = outf + (size_t)gr * ostride + cc * 8;
                    *(float4*)ptr = f0;
                    *(float4*)(ptr + 4) = f1;
                } else {
                    *(bf16x8*)(outb + (size_t)gr * ostride + cc * 8) = v;
                }
            }
        }
        __syncthreads();
    }
}

// ---------------- launch ----------------

static inline size_t align_up(size_t x, size_t a) { return (x + a - 1) & ~(a - 1); }

extern "C" void kernel_launch(void* const* d_in, const int* in_sizes, int n_in,
                              void* d_out, int out_size, void* d_ws, size_t ws_size,
                              hipStream_t stream) {
    const float* x   = (const float*)d_in[0];
    const int*   ei  = (const int*)d_in[1];
    const float* W1l = (const float*)d_in[2];
    const float* b1l = (const float*)d_in[3];
    const float* W1r = (const float*)d_in[4];
    const float* W2l = (const float*)d_in[5];
    const float* b2l = (const float*)d_in[6];
    const float* W2r = (const float*)d_in[7];

    int N = in_sizes[0] / DD;
    int E = in_sizes[1] / 2;
    int nbuck = (N + NPB - 1) / NPB;   // <= 512

    char* ws = (char*)d_ws;
    size_t off = 0;
    int* cnt = (int*)(ws + off);      off = align_up(off + (size_t)N * 4, 256);
    int* offs = (int*)(ws + off);     off = align_up(off + (size_t)(N + 1) * 4, 256);
    int* bcur = (int*)(ws + off);     off = align_up(off + (size_t)512 * 4, 256);
    int* part = (int*)(ws + off);     off = align_up(off + (size_t)64 * 4, 256);
    int* csr = (int*)(ws + off);      off = align_up(off + (size_t)E * 4, 256);
    int2* stage = (int2*)(ws + off);  off = align_up(off + (size_t)E * 8, 256);
    ushort_t* abuf = (ushort_t*)(ws + off);  off = align_up(off + (size_t)N * 512 * 2, 256);
    // gemm A-tile overreads up to 127 rows past N: wc1/wc2 give slack
    ushort_t* wc1 = (ushort_t*)(ws + off);   off = align_up(off + (size_t)256 * 512 * 2, 256);
    ushort_t* wc2 = (ushort_t*)(ws + off);   off = align_up(off + (size_t)256 * 512 * 2, 256);

    hipMemsetAsync(cnt, 0, (size_t)N * 4, stream);

    int xe = N * DD;
    int eb = (E + 255) / 256;
    int cxb = (xe / 8 + 255) / 256;
    int cwb = (4 * DD * DD / 8) / 256;
    prep_kernel<<<eb + cxb + cwb, 256, 0, stream>>>(ei, cnt, E, eb,
                                                    x, abuf, xe, cxb,
                                                    W1l, W1r, W2l, W2r, wc1, wc2);

    int nb = (N + 2047) / 2048;   // <= 64
    scan_partial_kernel<<<nb, 256, 0, stream>>>(cnt, part, N);
    scan_final_kernel<<<nb, 256, 0, stream>>>(cnt, part, offs, bcur, N, E, nb);

    int pb = (E + 2047) / 2048;
    part_kernel<<<pb, 256, 0, stream>>>(ei, bcur, stage, E, nbuck);
    group_kernel<<<nbuck, 256, 0, stream>>>(stage, offs, csr, N);

    int gb = (N + 127) / 128;
    int ab = (N + 3) / 4;

    // layer 1: agg x -> abuf[:,0:256]; gemm -> h into abuf[:,256:512] (bf16)
    agg_kernel<<<ab, 256, 0, stream>>>(abuf + 256, csr, offs, abuf, N);
    gemm_norm_kernel<<<gb, 512, 0, stream>>>(abuf, wc1, b1l,
                                             abuf + 256, (float*)nullptr, 512, N, 1);

    // layer 2: agg h -> abuf[:,0:256]; gemm -> d_out (fp32)
    agg_kernel<<<ab, 256, 0, stream>>>(abuf + 256, csr, offs, abuf, N);
    gemm_norm_kernel<<<gb, 512, 0, stream>>>(abuf, wc2, b2l,
                                             (ushort_t*)nullptr, (float*)d_out, DD, N, 0);
}